// Round 1
// baseline (134.660 us; speedup 1.0000x reference)
//
#include <hip/hip_runtime.h>
#include <stdint.h>

typedef __attribute__((ext_vector_type(8))) short bf16x8;
typedef __attribute__((ext_vector_type(4))) float f32x4;

#define B_ROWS 131072
#define BM 64
#define ZP 456   // z row pitch in bf16 elems (448 + 8 pad)
#define AP 136   // a1/a2 row pitch in bf16 elems (128 + 8 pad)

#define Z_OFF    0
#define Z_BYTES  (BM * ZP * 2)            // 58368
#define A1_OFF   (Z_OFF + Z_BYTES)        // 58368
#define A1_BYTES (BM * AP * 2)            // 17408
#define BIAS_OFF (A1_OFF + A1_BYTES)      // 75776
#define BIAS_BYTES (512 * 4)              // b1[128] b2[128] b3[256]
#define LDET_OFF (BIAS_OFF + BIAS_BYTES)  // 77824
#define LDS_TOTAL (LDET_OFF + 4 * 64 * 4) // 78848

// packed weight fragment offsets (in uint4 units)
#define W1P_OFF 0      // 8 ntiles * 14 ktiles * 64 lanes = 7168
#define W2P_OFF 7168   // 8 * 4 * 64 = 2048
#define W3P_OFF 9216   // 16 * 4 * 64 = 4096  -> total 13312 uint4 = 212992 B

__device__ inline uint16_t f2bf(float x) {
  uint32_t u = __float_as_uint(x);
  u += 0x7fffu + ((u >> 16) & 1u);   // round-to-nearest-even
  return (uint16_t)(u >> 16);
}

__device__ inline float tanh_fast(float x) {
  x = fminf(fmaxf(x, -15.f), 15.f);
  float e = __expf(2.f * x);
  return (e - 1.f) / (e + 1.f);
}

// Pack W (row-major KxN, f32) into bf16 MFMA-B fragment order:
// frag(nt,kt): lane l holds B[kt*32 + (l>>4)*8 + j][nt*16 + (l&15)], j=0..7
__global__ void prepack_kernel(const float* __restrict__ W1,
                               const float* __restrict__ W2,
                               const float* __restrict__ W3,
                               uint4* __restrict__ wp) {
  int tid = blockIdx.x * 256 + threadIdx.x;
  if (tid >= 13312) return;
  int l = tid & 63, f = tid >> 6;
  const float* W; int N, kt, nt;
  if (f < 112)      { W = W1; N = 128; int ff = f;       nt = ff / 14; kt = ff - nt * 14; }
  else if (f < 144) { W = W2; N = 128; int ff = f - 112; nt = ff >> 2; kt = ff & 3; }
  else              { W = W3; N = 256; int ff = f - 144; nt = ff >> 2; kt = ff & 3; }
  int k0  = kt * 32 + (l >> 4) * 8;
  int col = nt * 16 + (l & 15);
  uint16_t v[8];
#pragma unroll
  for (int j = 0; j < 8; j++) v[j] = f2bf(W[(size_t)(k0 + j) * N + col]);
  uint4 o;
  o.x = (uint32_t)v[0] | ((uint32_t)v[1] << 16);
  o.y = (uint32_t)v[2] | ((uint32_t)v[3] << 16);
  o.z = (uint32_t)v[4] | ((uint32_t)v[5] << 16);
  o.w = (uint32_t)v[6] | ((uint32_t)v[7] << 16);
  wp[tid] = o;
}

__global__ __launch_bounds__(256, 2) void fused_kernel(
    const float* __restrict__ x, const float* __restrict__ h,
    const float* __restrict__ b1, const float* __restrict__ b2,
    const float* __restrict__ b3, const uint4* __restrict__ wp,
    float* __restrict__ y, float* __restrict__ ldet) {
  extern __shared__ uint8_t smem[];
  uint16_t* zs  = (uint16_t*)(smem + Z_OFF);
  uint16_t* a1  = (uint16_t*)(smem + A1_OFF);
  uint16_t* a2  = (uint16_t*)(smem + Z_OFF);   // alias: z dead after GEMM1
  float*    bias = (float*)(smem + BIAS_OFF);
  float*    lsum = (float*)(smem + LDET_OFF);

  const int t  = threadIdx.x;
  const int m0 = blockIdx.x * BM;

  for (int i = t; i < 512; i += 256)
    bias[i] = (i < 128) ? b1[i] : (i < 256) ? b2[i - 128] : b3[i - 256];

  // ---- stage: x even cols -> z[:,0:128] bf16 ; h -> z[:,128:448] bf16
  {
    const float4* xg = (const float4*)(x + (size_t)m0 * 256);
#pragma unroll
    for (int k = 0; k < 16; k++) {
      int idx = t + k * 256;              // 0..4095 = 64 rows * 64 float4
      int row = idx >> 6, c4 = idx & 63;
      float4 v = xg[idx];
      uint32_t p = (uint32_t)f2bf(v.x) | ((uint32_t)f2bf(v.z) << 16);
      *(uint32_t*)&zs[row * ZP + c4 * 2] = p;
    }
    const float4* hg = (const float4*)(h + (size_t)m0 * 320);
#pragma unroll
    for (int k = 0; k < 20; k++) {
      int idx = t + k * 256;              // 0..5119 = 64 rows * 80 float4
      int row = idx / 80, c4 = idx - row * 80;
      float4 v = hg[idx];
      uint2 p;
      p.x = (uint32_t)f2bf(v.x) | ((uint32_t)f2bf(v.y) << 16);
      p.y = (uint32_t)f2bf(v.z) | ((uint32_t)f2bf(v.w) << 16);
      *(uint2*)&zs[row * ZP + 128 + c4 * 4] = p;
    }
  }
  __syncthreads();

  const int wid = t >> 6, l = t & 63;
  const int lr = l & 15, lq = l >> 4;

  // ---- GEMM1: a1 = relu(z(64x448) @ W1(448x128) + b1); wave owns 32 cols
  {
    f32x4 acc[4][2] = {};
#pragma unroll 2
    for (int kt = 0; kt < 14; kt++) {
      bf16x8 afr[4];
#pragma unroll
      for (int mi = 0; mi < 4; mi++)
        afr[mi] = *(const bf16x8*)&zs[(mi * 16 + lr) * ZP + kt * 32 + lq * 8];
      bf16x8 bfr[2];
#pragma unroll
      for (int nj = 0; nj < 2; nj++)
        bfr[nj] = *(const bf16x8*)&wp[W1P_OFF + ((wid * 2 + nj) * 14 + kt) * 64 + l];
#pragma unroll
      for (int mi = 0; mi < 4; mi++)
#pragma unroll
        for (int nj = 0; nj < 2; nj++)
          acc[mi][nj] = __builtin_amdgcn_mfma_f32_16x16x32_bf16(afr[mi], bfr[nj], acc[mi][nj], 0, 0, 0);
    }
#pragma unroll
    for (int mi = 0; mi < 4; mi++)
#pragma unroll
      for (int nj = 0; nj < 2; nj++) {
        int col = wid * 32 + nj * 16 + lr;
        float bv = bias[col];
#pragma unroll
        for (int r = 0; r < 4; r++) {
          int row = mi * 16 + lq * 4 + r;
          a1[row * AP + col] = f2bf(fmaxf(acc[mi][nj][r] + bv, 0.f));
        }
      }
  }
  __syncthreads();

  // ---- GEMM2: a2 = relu(a1 @ W2(128x128) + b2)
  {
    f32x4 acc[4][2] = {};
#pragma unroll
    for (int kt = 0; kt < 4; kt++) {
      bf16x8 afr[4];
#pragma unroll
      for (int mi = 0; mi < 4; mi++)
        afr[mi] = *(const bf16x8*)&a1[(mi * 16 + lr) * AP + kt * 32 + lq * 8];
      bf16x8 bfr[2];
#pragma unroll
      for (int nj = 0; nj < 2; nj++)
        bfr[nj] = *(const bf16x8*)&wp[W2P_OFF + ((wid * 2 + nj) * 4 + kt) * 64 + l];
#pragma unroll
      for (int mi = 0; mi < 4; mi++)
#pragma unroll
        for (int nj = 0; nj < 2; nj++)
          acc[mi][nj] = __builtin_amdgcn_mfma_f32_16x16x32_bf16(afr[mi], bfr[nj], acc[mi][nj], 0, 0, 0);
    }
    __syncthreads();   // all a1 reads done before a2 (aliases z... distinct, but keep order strict)
#pragma unroll
    for (int mi = 0; mi < 4; mi++)
#pragma unroll
      for (int nj = 0; nj < 2; nj++) {
        int col = wid * 32 + nj * 16 + lr;
        float bv = bias[128 + col];
#pragma unroll
        for (int r = 0; r < 4; r++) {
          int row = mi * 16 + lq * 4 + r;
          a2[row * AP + col] = f2bf(fmaxf(acc[mi][nj][r] + bv, 0.f));
        }
      }
  }
  __syncthreads();

  // ---- GEMM3: st = a2 @ W3(128x256) + b3 ; wave owns s-cols [32w,32w+32) and t-cols +128
  f32x4 acc3[4][4] = {};
#pragma unroll
  for (int kt = 0; kt < 4; kt++) {
    bf16x8 afr[4];
#pragma unroll
    for (int mi = 0; mi < 4; mi++)
      afr[mi] = *(const bf16x8*)&a2[(mi * 16 + lr) * AP + kt * 32 + lq * 8];
    bf16x8 bfr[4];
#pragma unroll
    for (int nj = 0; nj < 2; nj++) {
      bfr[nj]     = *(const bf16x8*)&wp[W3P_OFF + ((wid * 2 + nj) * 4 + kt) * 64 + l];
      bfr[nj + 2] = *(const bf16x8*)&wp[W3P_OFF + ((8 + wid * 2 + nj) * 4 + kt) * 64 + l];
    }
#pragma unroll
    for (int mi = 0; mi < 4; mi++)
#pragma unroll
      for (int nj = 0; nj < 4; nj++)
        acc3[mi][nj] = __builtin_amdgcn_mfma_f32_16x16x32_bf16(afr[mi], bfr[nj], acc3[mi][nj], 0, 0, 0);
  }

  // ---- epilogue: s=tanh, y pair-write, log_det partials
  float lp[4][4];
#pragma unroll
  for (int mi = 0; mi < 4; mi++)
#pragma unroll
    for (int r = 0; r < 4; r++) lp[mi][r] = 0.f;

#pragma unroll
  for (int mi = 0; mi < 4; mi++) {
#pragma unroll
    for (int nj = 0; nj < 2; nj++) {
      int colc = wid * 32 + nj * 16 + lr;   // 0..127
      float bs = bias[256 + colc];
      float bt = bias[384 + colc];
#pragma unroll
      for (int r = 0; r < 4; r++) {
        int grow = m0 + mi * 16 + lq * 4 + r;
        float sv = tanh_fast(acc3[mi][nj][r] + bs);
        float tv = acc3[mi][nj + 2][r] + bt;
        lp[mi][r] += sv;
        const float2 xv = *(const float2*)(x + (size_t)grow * 256 + 2 * colc);
        float2 o;
        o.x = xv.x;                               // exact pass-through
        o.y = xv.y * __expf(sv) + tv;
        *(float2*)(y + (size_t)grow * 256 + 2 * colc) = o;
      }
    }
  }

  // log_det: reduce 16 lanes (col dim) then combine 4 waves via LDS
#pragma unroll
  for (int mi = 0; mi < 4; mi++)
#pragma unroll
    for (int r = 0; r < 4; r++) {
      float v = lp[mi][r];
      v += __shfl_xor(v, 1);
      v += __shfl_xor(v, 2);
      v += __shfl_xor(v, 4);
      v += __shfl_xor(v, 8);
      if (lr == 0) lsum[wid * 64 + mi * 16 + lq * 4 + r] = v;
    }
  __syncthreads();
  if (t < 64) ldet[m0 + t] = lsum[t] + lsum[64 + t] + lsum[128 + t] + lsum[192 + t];
}

extern "C" void kernel_launch(void* const* d_in, const int* in_sizes, int n_in,
                              void* d_out, int out_size, void* d_ws, size_t ws_size,
                              hipStream_t stream) {
  const float* x  = (const float*)d_in[0];
  const float* h  = (const float*)d_in[1];
  const float* W1 = (const float*)d_in[2];
  const float* b1 = (const float*)d_in[3];
  const float* W2 = (const float*)d_in[4];
  const float* b2 = (const float*)d_in[5];
  const float* W3 = (const float*)d_in[6];
  const float* b3 = (const float*)d_in[7];
  float* y    = (float*)d_out;
  float* ldet = y + (size_t)B_ROWS * 256;
  uint4* wp   = (uint4*)d_ws;

  prepack_kernel<<<52, 256, 0, stream>>>(W1, W2, W3, wp);

  hipFuncSetAttribute((const void*)fused_kernel,
                      hipFuncAttributeMaxDynamicSharedMemorySize, LDS_TOTAL);
  fused_kernel<<<B_ROWS / BM, 256, LDS_TOTAL, stream>>>(x, h, b1, b2, b3, wp, y, ldet);
}

// Round 2
// 122.718 us; speedup vs baseline: 1.0973x; 1.0973x over previous
//
#include <hip/hip_runtime.h>
#include <stdint.h>

typedef __attribute__((ext_vector_type(8))) short bf16x8;
typedef __attribute__((ext_vector_type(4))) float f32x4;

#define B_ROWS 131072
#define BM 32
#define ZP 456   // z row pitch in bf16 elems (448 + 8 pad)
#define AP 136   // a1/a2 row pitch in bf16 elems (128 + 8 pad)

#define Z_OFF    0
#define Z_BYTES  (BM * ZP * 2)            // 29184
#define A1_OFF   (Z_OFF + Z_BYTES)        // 29184
#define A1_BYTES (BM * AP * 2)            // 8704
#define BIAS_OFF (A1_OFF + A1_BYTES)      // 37888
#define BIAS_BYTES (512 * 4)              // b1[128] b2[128] b3[256]
#define LDET_OFF (BIAS_OFF + BIAS_BYTES)  // 39936
#define LDS_TOTAL (LDET_OFF + 4 * BM * 4) // 40448 -> 4 blocks/CU

// packed weight fragment offsets (in uint4 units)
#define W1P_OFF 0      // 8 ntiles * 14 ktiles * 64 lanes = 7168
#define W2P_OFF 7168   // 8 * 4 * 64 = 2048
#define W3P_OFF 9216   // 16 * 4 * 64 = 4096  -> total 13312 uint4

__device__ inline uint16_t f2bf(float x) {
  uint32_t u = __float_as_uint(x);
  u += 0x7fffu + ((u >> 16) & 1u);   // round-to-nearest-even
  return (uint16_t)(u >> 16);
}

__device__ inline float tanh_fast(float x) {
  x = fminf(fmaxf(x, -15.f), 15.f);
  float e = __expf(2.f * x);
  return (e - 1.f) / (e + 1.f);
}

// Pack W (row-major KxN, f32) into bf16 MFMA-B fragment order:
// frag(nt,kt): lane l holds B[kt*32 + (l>>4)*8 + j][nt*16 + (l&15)], j=0..7
__global__ void prepack_kernel(const float* __restrict__ W1,
                               const float* __restrict__ W2,
                               const float* __restrict__ W3,
                               uint4* __restrict__ wp) {
  int tid = blockIdx.x * 256 + threadIdx.x;
  if (tid >= 13312) return;
  int l = tid & 63, f = tid >> 6;
  const float* W; int N, kt, nt;
  if (f < 112)      { W = W1; N = 128; int ff = f;       nt = ff / 14; kt = ff - nt * 14; }
  else if (f < 144) { W = W2; N = 128; int ff = f - 112; nt = ff >> 2; kt = ff & 3; }
  else              { W = W3; N = 256; int ff = f - 144; nt = ff >> 2; kt = ff & 3; }
  int k0  = kt * 32 + (l >> 4) * 8;
  int col = nt * 16 + (l & 15);
  uint16_t v[8];
#pragma unroll
  for (int j = 0; j < 8; j++) v[j] = f2bf(W[(size_t)(k0 + j) * N + col]);
  uint4 o;
  o.x = (uint32_t)v[0] | ((uint32_t)v[1] << 16);
  o.y = (uint32_t)v[2] | ((uint32_t)v[3] << 16);
  o.z = (uint32_t)v[4] | ((uint32_t)v[5] << 16);
  o.w = (uint32_t)v[6] | ((uint32_t)v[7] << 16);
  wp[tid] = o;
}

__global__ __launch_bounds__(256, 4) void fused_kernel(
    const float* __restrict__ x, const float* __restrict__ h,
    const float* __restrict__ b1, const float* __restrict__ b2,
    const float* __restrict__ b3, const uint4* __restrict__ wp,
    float* __restrict__ y, float* __restrict__ ldet) {
  extern __shared__ uint8_t smem[];
  uint16_t* zs  = (uint16_t*)(smem + Z_OFF);
  uint16_t* a1  = (uint16_t*)(smem + A1_OFF);
  uint16_t* a2  = (uint16_t*)(smem + Z_OFF);   // alias: z dead after GEMM1
  float*    bias = (float*)(smem + BIAS_OFF);
  float*    lsum = (float*)(smem + LDET_OFF);

  const int t  = threadIdx.x;
  const int m0 = blockIdx.x * BM;

  for (int i = t; i < 512; i += 256)
    bias[i] = (i < 128) ? b1[i] : (i < 256) ? b2[i - 128] : b3[i - 256];

  // ---- stage: x even cols -> z[:,0:128] bf16 ; h -> z[:,128:448] bf16
  {
    const float4* xg = (const float4*)(x + (size_t)m0 * 256);
#pragma unroll
    for (int k = 0; k < 8; k++) {
      int idx = t + k * 256;              // 0..2047 = 32 rows * 64 float4
      int row = idx >> 6, c4 = idx & 63;
      float4 v = xg[idx];
      uint32_t p = (uint32_t)f2bf(v.x) | ((uint32_t)f2bf(v.z) << 16);
      *(uint32_t*)&zs[row * ZP + c4 * 2] = p;
    }
    const float4* hg = (const float4*)(h + (size_t)m0 * 320);
#pragma unroll
    for (int k = 0; k < 10; k++) {
      int idx = t + k * 256;              // 0..2559 = 32 rows * 80 float4
      int row = idx / 80, c4 = idx - row * 80;
      float4 v = hg[idx];
      uint2 p;
      p.x = (uint32_t)f2bf(v.x) | ((uint32_t)f2bf(v.y) << 16);
      p.y = (uint32_t)f2bf(v.z) | ((uint32_t)f2bf(v.w) << 16);
      *(uint2*)&zs[row * ZP + 128 + c4 * 4] = p;
    }
  }
  __syncthreads();

  const int wid = t >> 6, l = t & 63;
  const int lr = l & 15, lq = l >> 4;

  // ---- GEMM1: a1 = relu(z(32x448) @ W1(448x128) + b1); wave owns 32 cols
  {
    f32x4 acc[2][2] = {};
#pragma unroll 2
    for (int kt = 0; kt < 14; kt++) {
      bf16x8 afr[2];
#pragma unroll
      for (int mi = 0; mi < 2; mi++)
        afr[mi] = *(const bf16x8*)&zs[(mi * 16 + lr) * ZP + kt * 32 + lq * 8];
      bf16x8 bfr[2];
#pragma unroll
      for (int nj = 0; nj < 2; nj++)
        bfr[nj] = *(const bf16x8*)&wp[W1P_OFF + ((wid * 2 + nj) * 14 + kt) * 64 + l];
#pragma unroll
      for (int mi = 0; mi < 2; mi++)
#pragma unroll
        for (int nj = 0; nj < 2; nj++)
          acc[mi][nj] = __builtin_amdgcn_mfma_f32_16x16x32_bf16(afr[mi], bfr[nj], acc[mi][nj], 0, 0, 0);
    }
#pragma unroll
    for (int mi = 0; mi < 2; mi++)
#pragma unroll
      for (int nj = 0; nj < 2; nj++) {
        int col = wid * 32 + nj * 16 + lr;
        float bv = bias[col];
#pragma unroll
        for (int r = 0; r < 4; r++) {
          int row = mi * 16 + lq * 4 + r;
          a1[row * AP + col] = f2bf(fmaxf(acc[mi][nj][r] + bv, 0.f));
        }
      }
  }
  __syncthreads();

  // ---- GEMM2: a2 = relu(a1 @ W2(128x128) + b2)
  {
    f32x4 acc[2][2] = {};
#pragma unroll
    for (int kt = 0; kt < 4; kt++) {
      bf16x8 afr[2];
#pragma unroll
      for (int mi = 0; mi < 2; mi++)
        afr[mi] = *(const bf16x8*)&a1[(mi * 16 + lr) * AP + kt * 32 + lq * 8];
      bf16x8 bfr[2];
#pragma unroll
      for (int nj = 0; nj < 2; nj++)
        bfr[nj] = *(const bf16x8*)&wp[W2P_OFF + ((wid * 2 + nj) * 4 + kt) * 64 + l];
#pragma unroll
      for (int mi = 0; mi < 2; mi++)
#pragma unroll
        for (int nj = 0; nj < 2; nj++)
          acc[mi][nj] = __builtin_amdgcn_mfma_f32_16x16x32_bf16(afr[mi], bfr[nj], acc[mi][nj], 0, 0, 0);
    }
    __syncthreads();   // a1 reads done before a2 overwrite (a2 aliases z region)
#pragma unroll
    for (int mi = 0; mi < 2; mi++)
#pragma unroll
      for (int nj = 0; nj < 2; nj++) {
        int col = wid * 32 + nj * 16 + lr;
        float bv = bias[128 + col];
#pragma unroll
        for (int r = 0; r < 4; r++) {
          int row = mi * 16 + lq * 4 + r;
          a2[row * AP + col] = f2bf(fmaxf(acc[mi][nj][r] + bv, 0.f));
        }
      }
  }
  __syncthreads();

  // ---- prefetch epilogue x pairs (address-only dependence; hides under GEMM3)
  float2 xv[2][2][4];
#pragma unroll
  for (int mi = 0; mi < 2; mi++)
#pragma unroll
    for (int nj = 0; nj < 2; nj++) {
      int colc = wid * 32 + nj * 16 + lr;
#pragma unroll
      for (int r = 0; r < 4; r++) {
        int grow = m0 + mi * 16 + lq * 4 + r;
        xv[mi][nj][r] = *(const float2*)(x + (size_t)grow * 256 + 2 * colc);
      }
    }

  // ---- GEMM3: st = a2 @ W3(128x256) + b3 ; wave owns s-cols [32w,32w+32) and t-cols +128
  f32x4 acc3[2][4] = {};
#pragma unroll
  for (int kt = 0; kt < 4; kt++) {
    bf16x8 afr[2];
#pragma unroll
    for (int mi = 0; mi < 2; mi++)
      afr[mi] = *(const bf16x8*)&a2[(mi * 16 + lr) * AP + kt * 32 + lq * 8];
    bf16x8 bfr[4];
#pragma unroll
    for (int nj = 0; nj < 2; nj++) {
      bfr[nj]     = *(const bf16x8*)&wp[W3P_OFF + ((wid * 2 + nj) * 4 + kt) * 64 + l];
      bfr[nj + 2] = *(const bf16x8*)&wp[W3P_OFF + ((8 + wid * 2 + nj) * 4 + kt) * 64 + l];
    }
#pragma unroll
    for (int mi = 0; mi < 2; mi++)
#pragma unroll
      for (int nj = 0; nj < 4; nj++)
        acc3[mi][nj] = __builtin_amdgcn_mfma_f32_16x16x32_bf16(afr[mi], bfr[nj], acc3[mi][nj], 0, 0, 0);
  }

  // ---- epilogue: s=tanh, y pair-write, log_det partials
  float lp[2][4];
#pragma unroll
  for (int mi = 0; mi < 2; mi++)
#pragma unroll
    for (int r = 0; r < 4; r++) lp[mi][r] = 0.f;

#pragma unroll
  for (int mi = 0; mi < 2; mi++) {
#pragma unroll
    for (int nj = 0; nj < 2; nj++) {
      int colc = wid * 32 + nj * 16 + lr;   // 0..127
      float bs = bias[256 + colc];
      float bt = bias[384 + colc];
#pragma unroll
      for (int r = 0; r < 4; r++) {
        int grow = m0 + mi * 16 + lq * 4 + r;
        float sv = tanh_fast(acc3[mi][nj][r] + bs);
        float tv = acc3[mi][nj + 2][r] + bt;
        lp[mi][r] += sv;
        float2 o;
        o.x = xv[mi][nj][r].x;                         // exact pass-through
        o.y = xv[mi][nj][r].y * __expf(sv) + tv;
        *(float2*)(y + (size_t)grow * 256 + 2 * colc) = o;
      }
    }
  }

  // log_det: reduce 16 lanes (col dim) then combine 4 waves via LDS
#pragma unroll
  for (int mi = 0; mi < 2; mi++)
#pragma unroll
    for (int r = 0; r < 4; r++) {
      float v = lp[mi][r];
      v += __shfl_xor(v, 1);
      v += __shfl_xor(v, 2);
      v += __shfl_xor(v, 4);
      v += __shfl_xor(v, 8);
      if (lr == 0) lsum[wid * BM + mi * 16 + lq * 4 + r] = v;
    }
  __syncthreads();
  if (t < BM) ldet[m0 + t] = lsum[t] + lsum[BM + t] + lsum[2 * BM + t] + lsum[3 * BM + t];
}

extern "C" void kernel_launch(void* const* d_in, const int* in_sizes, int n_in,
                              void* d_out, int out_size, void* d_ws, size_t ws_size,
                              hipStream_t stream) {
  const float* x  = (const float*)d_in[0];
  const float* h  = (const float*)d_in[1];
  const float* W1 = (const float*)d_in[2];
  const float* b1 = (const float*)d_in[3];
  const float* W2 = (const float*)d_in[4];
  const float* b2 = (const float*)d_in[5];
  const float* W3 = (const float*)d_in[6];
  const float* b3 = (const float*)d_in[7];
  float* y    = (float*)d_out;
  float* ldet = y + (size_t)B_ROWS * 256;
  uint4* wp   = (uint4*)d_ws;

  prepack_kernel<<<52, 256, 0, stream>>>(W1, W2, W3, wp);

  hipFuncSetAttribute((const void*)fused_kernel,
                      hipFuncAttributeMaxDynamicSharedMemorySize, LDS_TOTAL);
  fused_kernel<<<B_ROWS / BM, 256, LDS_TOTAL, stream>>>(x, h, b1, b2, b3, wp, y, ldet);
}